// Round 4
// baseline (186.440 us; speedup 1.0000x reference)
//
#include <hip/hip_runtime.h>
#include <hip/hip_bf16.h>

#define B_ 2
#define N_ 1024
#define T_ 4096
#define H_ 256
#define ROWS_ 8192  // B*T

typedef float f32x4 __attribute__((ext_vector_type(4)));
typedef __bf16 bf16x8 __attribute__((ext_vector_type(8)));

__device__ __forceinline__ void gl16(const void* g, void* l) {
  __builtin_amdgcn_global_load_lds(
      (const __attribute__((address_space(1))) void*)g,
      (__attribute__((address_space(3))) void*)l, 16, 0, 0);
}

// ---------------- weight fp32 -> bf16 hi/lo split ----------------
__global__ __launch_bounds__(256) void cvt_split(
    const float* __restrict__ w1, const float* __restrict__ w2,
    __bf16* __restrict__ w1h, __bf16* __restrict__ w1l,
    __bf16* __restrict__ w2h, __bf16* __restrict__ w2l) {
  int i = blockIdx.x * 256 + threadIdx.x;
  if (i < 262144) {
    float v = w1[i];
    __bf16 h = (__bf16)v;
    w1h[i] = h;
    w1l[i] = (__bf16)(v - (float)h);
  } else {
    int j = i - 262144;
    float v = w2[j];
    __bf16 h = (__bf16)v;
    w2h[j] = h;
    w2l[j] = (__bf16)(v - (float)h);
  }
}

// ---------------- depthwise conv1d -> t-major h0 (hi/lo bf16) ----------------
__global__ __launch_bounds__(256) void dwconv_t(
    const float* __restrict__ x, const float* __restrict__ w,
    const float* __restrict__ bias, __bf16* __restrict__ h0h,
    __bf16* __restrict__ h0l) {
  __shared__ float xs[64][76];
  const int tid = threadIdx.x;
  const int t0 = blockIdx.x * 64;
  const int n0 = blockIdx.y * 64;
  const int b = blockIdx.z;
  for (int i = tid; i < 64 * 72; i += 256) {
    int rr = i / 72, cc = i % 72;
    int tt = t0 - 4 + cc;
    xs[rr][cc] = (tt >= 0 && tt < T_) ? x[((size_t)(b * N_ + n0 + rr)) * T_ + tt] : 0.f;
  }
  const int nl = tid & 63;
  const int tg = tid >> 6;
  float wr[9];
  #pragma unroll
  for (int k = 0; k < 9; ++k) wr[k] = w[(n0 + nl) * 9 + k];
  const float bb = bias[n0 + nl];
  __syncthreads();
  float win[24];
  #pragma unroll
  for (int c = 0; c < 6; ++c)
    *(f32x4*)&win[c * 4] = *(const f32x4*)&xs[nl][tg * 16 + c * 4];
  const size_t obase = ((size_t)b * T_ + t0 + tg * 16) * N_ + n0 + nl;
  #pragma unroll
  for (int j = 0; j < 16; ++j) {
    float acc = bb;
    #pragma unroll
    for (int k = 0; k < 9; ++k) acc = fmaf(win[j + k], wr[k], acc);
    __bf16 h = (__bf16)acc;
    h0h[obase + (size_t)j * N_] = h;
    h0l[obase + (size_t)j * N_] = (__bf16)(acc - (float)h);
  }
}

// ---------------- fused encoder: gemm1 -> gemm2 -> heads ----------------
// block: 32 t-rows x full H=256. 8 waves (2t x 4g), 3-pass split-bf16 MFMA.
// LDS: As 8KB | Ws 64KB (aliased by h2 f32 later) | h1 32KB | wmvT 20KB
__global__ __launch_bounds__(512) void encoder_fused(
    const __bf16* __restrict__ Ah, const __bf16* __restrict__ Al,
    const __bf16* __restrict__ W1h, const __bf16* __restrict__ W1l,
    const float* __restrict__ b1,
    const __bf16* __restrict__ W2h, const __bf16* __restrict__ W2l,
    const float* __restrict__ b2,
    const float* __restrict__ wm, const float* __restrict__ bm,
    const float* __restrict__ wv, const float* __restrict__ bv,
    float* __restrict__ out_mu, float* __restrict__ out_lv) {
  __shared__ __attribute__((aligned(16))) char smem[126976];
  char* const ASB = smem;                      // [buf:4096][plane:2048], rows 64B
  char* const WSB = smem + 8192;               // [buf:32768][plane:16384], rows 64B
  char* const H1B = smem + 73728;              // [plane:16384], rows 512B
  float* const WMV = (float*)(smem + 106496);  // [256][20] f32
  float* const H2S = (float*)(smem + 8192);    // alias Ws: [32][264] f32

  const int tid = threadIdx.x;
  const int row0 = blockIdx.x * 32;
  const int lane = tid & 63;
  const int wid = tid >> 6;
  const int wt = (wid >> 2) * 16;  // wave t-offset (0/16)
  const int wg = (wid & 3) * 64;   // wave g-offset
  const int lr = lane & 15;
  const int ls = lane >> 4;

  // stage wm/wv transposed: WMV[k][o]
  if (tid < 256) {
    #pragma unroll
    for (int i = 0; i < 8; ++i) WMV[tid * 20 + i] = wm[i * 256 + tid];
    #pragma unroll
    for (int i = 0; i < 4; ++i) WMV[tid * 20 + 8 + i] = wv[i * 256 + tid];
  }

  float b1g[4], b2g[4];
  #pragma unroll
  for (int ni = 0; ni < 4; ++ni) {
    b1g[ni] = b1[wg + ni * 16 + lr];
    b2g[ni] = b2[wg + ni * 16 + lr];
  }

  // A staging map (tid<256): plane=tid>>7, idx=tid&127 -> row=idx>>2, chunk=idx&3
  const int a_pl = tid >> 7;
  const int a_idx = tid & 127;
  const int a_r = a_idx >> 2;
  const int a_c = (a_idx & 3) ^ ((a_r >> 1) & 3);  // source-side XOR swizzle
  const __bf16* a_src = (a_pl ? Al : Ah) + (size_t)(row0 + a_r) * 1024 + a_c * 8;
  char* const a_dst = ASB + a_pl * 2048 + a_idx * 16;

  auto STAGE_A = [&](int buf, int kt) {
    if (tid < 256) gl16(a_src + kt * 32, a_dst + buf * 4096);
  };
  auto STAGE_W = [&](int buf, int k0, const __bf16* Wh, const __bf16* Wl, int K) {
    #pragma unroll
    for (int j = 0; j < 4; ++j) {
      const int s = tid + j * 512;
      const int pl = s >> 10;
      const int idx = s & 1023;
      const int g = idx >> 2;
      const int c = (idx & 3) ^ ((g >> 1) & 3);
      gl16((pl ? Wl : Wh) + (size_t)g * K + k0 + c * 8, WSB + buf * 32768 + s * 16);
    }
  };
  auto FR_A = [&](int cur, int pl, int r) {
    return *(const bf16x8*)(ASB + cur * 4096 + pl * 2048 + r * 64 +
                            (ls ^ ((r >> 1) & 3)) * 16);
  };
  auto FR_W = [&](int cur, int pl, int g) {
    return *(const bf16x8*)(WSB + cur * 32768 + pl * 16384 + g * 64 +
                            (ls ^ ((g >> 1) & 3)) * 16);
  };

  f32x4 acc[4];
  #pragma unroll
  for (int i = 0; i < 4; ++i) acc[i] = (f32x4)0.f;

  // ---- gemm1: K=1024, 32 kt ----
  STAGE_A(0, 0);
  STAGE_W(0, 0, W1h, W1l, 1024);
  __syncthreads();
  for (int kt = 0; kt < 32; ++kt) {
    const int cur = kt & 1;
    if (kt + 1 < 32) {
      STAGE_A(cur ^ 1, kt + 1);
      STAGE_W(cur ^ 1, (kt + 1) * 32, W1h, W1l, 1024);
    }
    bf16x8 ah = FR_A(cur, 0, wt + lr);
    bf16x8 al = FR_A(cur, 1, wt + lr);
    #pragma unroll
    for (int ni = 0; ni < 4; ++ni) {
      bf16x8 wh = FR_W(cur, 0, wg + ni * 16 + lr);
      bf16x8 wl = FR_W(cur, 1, wg + ni * 16 + lr);
      acc[ni] = __builtin_amdgcn_mfma_f32_16x16x32_bf16(ah, wh, acc[ni], 0, 0, 0);
      acc[ni] = __builtin_amdgcn_mfma_f32_16x16x32_bf16(ah, wl, acc[ni], 0, 0, 0);
      acc[ni] = __builtin_amdgcn_mfma_f32_16x16x32_bf16(al, wh, acc[ni], 0, 0, 0);
    }
    __syncthreads();
  }

  // ---- epilogue 1 -> h1 LDS (hi/lo, 512B rows, (t&7) chunk swizzle) ----
  #pragma unroll
  for (int ni = 0; ni < 4; ++ni) {
    const int g = wg + ni * 16 + lr;
    const int c = g >> 3;
    #pragma unroll
    for (int reg = 0; reg < 4; ++reg) {
      const int t = wt + ls * 4 + reg;
      float v = fmaxf(acc[ni][reg] + b1g[ni], 0.f);
      __bf16 h = (__bf16)v;
      const int off = t * 512 + ((c ^ (t & 7)) * 16) + (g & 7) * 2;
      *(__bf16*)(H1B + off) = h;
      *(__bf16*)(H1B + 16384 + off) = (__bf16)(v - (float)h);
    }
    acc[ni] = (f32x4)0.f;
  }
  STAGE_W(0, 0, W2h, W2l, 256);
  __syncthreads();

  // ---- gemm2: K=256, 8 kt ----
  for (int kt = 0; kt < 8; ++kt) {
    const int cur = kt & 1;
    if (kt + 1 < 8) STAGE_W(cur ^ 1, (kt + 1) * 32, W2h, W2l, 256);
    const int t = wt + lr;
    const int ca = ((kt * 4 + ls) ^ (t & 7)) * 16;
    bf16x8 ah = *(const bf16x8*)(H1B + t * 512 + ca);
    bf16x8 al = *(const bf16x8*)(H1B + 16384 + t * 512 + ca);
    #pragma unroll
    for (int ni = 0; ni < 4; ++ni) {
      bf16x8 wh = FR_W(cur, 0, wg + ni * 16 + lr);
      bf16x8 wl = FR_W(cur, 1, wg + ni * 16 + lr);
      acc[ni] = __builtin_amdgcn_mfma_f32_16x16x32_bf16(ah, wh, acc[ni], 0, 0, 0);
      acc[ni] = __builtin_amdgcn_mfma_f32_16x16x32_bf16(ah, wl, acc[ni], 0, 0, 0);
      acc[ni] = __builtin_amdgcn_mfma_f32_16x16x32_bf16(al, wh, acc[ni], 0, 0, 0);
    }
    __syncthreads();
  }

  // ---- epilogue 2 -> h2 f32 in LDS (aliases Ws; safe after final barrier) ----
  #pragma unroll
  for (int ni = 0; ni < 4; ++ni) {
    const int g = wg + ni * 16 + lr;
    #pragma unroll
    for (int reg = 0; reg < 4; ++reg) {
      const int t = wt + ls * 4 + reg;
      H2S[t * 264 + g] = fmaxf(acc[ni][reg] + b2g[ni], 0.f);
    }
  }
  __syncthreads();

  // ---- heads: 16 threads per t-row, k = sub + 16j ----
  const int ht = tid >> 4;
  const int sub = tid & 15;
  float s[12];
  #pragma unroll
  for (int o = 0; o < 12; ++o) s[o] = 0.f;
  #pragma unroll
  for (int j = 0; j < 16; ++j) {
    const int k = sub + j * 16;
    const float hv = H2S[ht * 264 + k];
    const float* wp = &WMV[k * 20];
    #pragma unroll
    for (int o = 0; o < 12; ++o) s[o] = fmaf(wp[o], hv, s[o]);
  }
  #pragma unroll
  for (int o = 0; o < 12; ++o) {
    s[o] += __shfl_xor(s[o], 1);
    s[o] += __shfl_xor(s[o], 2);
    s[o] += __shfl_xor(s[o], 4);
    s[o] += __shfl_xor(s[o], 8);
  }
  const size_t row = row0 + ht;
  if (sub == 0) {
    float mm[8];
    #pragma unroll
    for (int ed = 0; ed < 4; ++ed) {
      float m0 = s[ed * 2] + bm[ed * 2];
      float m1 = s[ed * 2 + 1] + bm[ed * 2 + 1];
      float inv = 1.f / sqrtf(m0 * m0 + m1 * m1);
      mm[ed * 2] = m0 * inv;
      mm[ed * 2 + 1] = m1 * inv;
    }
    *(float4*)&out_mu[row * 8] = make_float4(mm[0], mm[1], mm[2], mm[3]);
    *(float4*)&out_mu[row * 8 + 4] = make_float4(mm[4], mm[5], mm[6], mm[7]);
  } else if (sub == 1) {
    *(float4*)&out_lv[row * 4] =
        make_float4(s[8] + bv[0], s[9] + bv[1], s[10] + bv[2], s[11] + bv[3]);
  }
}

// ---------------- responses + z copy (4 t per thread, 1KB stores) ----------------
__global__ __launch_bounds__(256) void resp_kernel(
    const float* __restrict__ z, const float* __restrict__ rf,
    const float* __restrict__ ew, const float* __restrict__ fs,
    const float* __restrict__ ltw, float* __restrict__ out,
    float* __restrict__ out_z) {
  __shared__ float s_sin[32][4], s_cos[32][4], s_w[32][2];
  const int tid = threadIdx.x;
  const int tc = blockIdx.x;  // 0..3
  const int nc = blockIdx.y;  // 0..31
  const int b = blockIdx.z;
  if (tid < 128) {
    int nl = tid >> 2, ed = tid & 3;
    float a = rf[(nc * 32 + nl) * 4 + ed];
    s_sin[nl][ed] = sinf(a);
    s_cos[nl][ed] = cosf(a);
  }
  if (tid < 32) {
    int n = nc * 32 + tid;
    float e0 = ew[n * 2], e1 = ew[n * 2 + 1];
    float m = fmaxf(e0, e1);
    float x0 = expf(e0 - m), x1 = expf(e1 - m);
    float sc = expf(fs[n]) / (x0 + x1);
    s_w[tid][0] = x0 * sc;
    s_w[tid][1] = x1 * sc;
  }
  __syncthreads();
  const int t = tc * 1024 + (tid >> 6) * 256 + (tid & 63) * 4;
  const float inv_tw = expf(-ltw[0]);
  float sz[16], cz[16];
  #pragma unroll
  for (int j = 0; j < 4; ++j) {
    float4 zv = *(const float4*)&z[((size_t)b * T_ + t + j) * 4];
    if (nc == 0) *(float4*)&out_z[((size_t)b * T_ + t + j) * 4] = zv;
    sz[j * 4 + 0] = sinf(zv.x); cz[j * 4 + 0] = cosf(zv.x);
    sz[j * 4 + 1] = sinf(zv.y); cz[j * 4 + 1] = cosf(zv.y);
    sz[j * 4 + 2] = sinf(zv.z); cz[j * 4 + 2] = cosf(zv.z);
    sz[j * 4 + 3] = sinf(zv.w); cz[j * 4 + 3] = cosf(zv.w);
  }
  float* op = out + (size_t)b * N_ * T_ + (size_t)(nc * 32) * T_ + t;
  for (int nl = 0; nl < 32; ++nl) {
    const float ss0 = s_sin[nl][0], sc0 = s_cos[nl][0];
    const float ss1 = s_sin[nl][1], sc1 = s_cos[nl][1];
    const float ss2 = s_sin[nl][2], sc2 = s_cos[nl][2];
    const float ss3 = s_sin[nl][3], sc3 = s_cos[nl][3];
    const float w0 = s_w[nl][0], w1 = s_w[nl][1];
    float o[4];
    #pragma unroll
    for (int j = 0; j < 4; ++j) {
      float d0 = sz[j * 4] * ss0 + cz[j * 4] * sc0 + sz[j * 4 + 1] * ss1 + cz[j * 4 + 1] * sc1;
      float d1 = sz[j * 4 + 2] * ss2 + cz[j * 4 + 2] * sc2 + sz[j * 4 + 3] * ss3 + cz[j * 4 + 3] * sc3;
      float r0 = __expf((2.f * d0 - 4.f) * inv_tw);
      float r1 = __expf((2.f * d1 - 4.f) * inv_tw);
      o[j] = w0 * r0 + w1 * r1;
    }
    *(float4*)&op[(size_t)nl * T_] = make_float4(o[0], o[1], o[2], o[3]);
  }
}

extern "C" void kernel_launch(void* const* d_in, const int* in_sizes, int n_in,
                              void* d_out, int out_size, void* d_ws, size_t ws_size,
                              hipStream_t stream) {
  const float* x   = (const float*)d_in[0];
  const float* z   = (const float*)d_in[1];
  const float* dww = (const float*)d_in[2];
  const float* dwb = (const float*)d_in[3];
  const float* w1  = (const float*)d_in[4];
  const float* b1  = (const float*)d_in[5];
  const float* w2  = (const float*)d_in[6];
  const float* b2  = (const float*)d_in[7];
  const float* wm  = (const float*)d_in[8];
  const float* bm  = (const float*)d_in[9];
  const float* wv  = (const float*)d_in[10];
  const float* bv  = (const float*)d_in[11];
  const float* rf  = (const float*)d_in[12];
  const float* ew  = (const float*)d_in[13];
  const float* fs  = (const float*)d_in[14];
  const float* ltw = (const float*)d_in[15];

  float* out = (float*)d_out;
  float* out_resp = out;                          // [B,N,T]
  float* out_z    = out + (size_t)B_ * N_ * T_;   // [B,T,2,2]
  float* out_mu   = out_z + (size_t)B_ * T_ * 4;  // [B,T,2,2,2]
  float* out_lv   = out_mu + (size_t)B_ * T_ * 8; // [B,T,2,2]

  // h0 hi/lo planes live in the responses output region (same 33.55MB),
  // dead before resp_kernel runs (stream-ordered).
  __bf16* h0h = (__bf16*)out_resp;
  __bf16* h0l = h0h + (size_t)ROWS_ * N_;

  __bf16* p = (__bf16*)d_ws;
  __bf16* w1h = p; p += 262144;
  __bf16* w1l = p; p += 262144;
  __bf16* w2h = p; p += 65536;
  __bf16* w2l = p; p += 65536;

  cvt_split<<<1280, 256, 0, stream>>>(w1, w2, w1h, w1l, w2h, w2l);
  dwconv_t<<<dim3(T_ / 64, N_ / 64, B_), 256, 0, stream>>>(x, dww, dwb, h0h, h0l);
  encoder_fused<<<dim3(ROWS_ / 32), 512, 0, stream>>>(
      h0h, h0l, w1h, w1l, b1, w2h, w2l, b2, wm, bm, wv, bv, out_mu, out_lv);
  resp_kernel<<<dim3(4, 32, 2), 256, 0, stream>>>(
      z, rf, ew, fs, ltw, out_resp, out_z);
}

// Round 6
// 175.848 us; speedup vs baseline: 1.0602x; 1.0602x over previous
//
#include <hip/hip_runtime.h>
#include <hip/hip_bf16.h>

#define B_ 2
#define N_ 1024
#define T_ 4096
#define H_ 256
#define ROWS_ 8192  // B*T

typedef float f32x4 __attribute__((ext_vector_type(4)));
typedef __bf16 bf16x8 __attribute__((ext_vector_type(8)));

__device__ __forceinline__ void gl16(const void* g, void* l) {
  __builtin_amdgcn_global_load_lds(
      (const __attribute__((address_space(1))) void*)g,
      (__attribute__((address_space(3))) void*)l, 16, 0, 0);
}

#define WAITV(N) asm volatile("s_waitcnt vmcnt(" #N ")" ::: "memory")
#define FENCE_ALL() asm volatile("s_waitcnt vmcnt(0) lgkmcnt(0)" ::: "memory")
#define LGKM0() asm volatile("s_waitcnt lgkmcnt(0)" ::: "memory")

// ---------------- pack W1/W2 into LDS-staging order (hi/lo bf16) ----------------
// slot s (0..2047) of k-tile kt: pl=s>>10, idx=s&1023, g=idx>>2,
// cc=(idx&3)^((g>>1)&3); content = plane_pl(W[g][kt*32+cc*8 .. +8))
__global__ __launch_bounds__(256) void cvt_pack(
    const float* __restrict__ w1, const float* __restrict__ w2,
    __bf16* __restrict__ w1p, __bf16* __restrict__ w2p) {
  const int i = blockIdx.x * 256 + threadIdx.x;
  const float* src;
  __bf16* dst;
  int K, kt, s;
  if (i < 65536) {
    kt = i >> 11; s = i & 2047; src = w1; K = 1024; dst = w1p + (size_t)i * 8;
  } else {
    int j = i - 65536;
    kt = j >> 11; s = j & 2047; src = w2; K = 256; dst = w2p + (size_t)j * 8;
  }
  const int pl = s >> 10;
  const int idx = s & 1023;
  const int g = idx >> 2;
  const int cc = (idx & 3) ^ ((g >> 1) & 3);
  const float* p = src + (size_t)g * K + kt * 32 + cc * 8;
  bf16x8 o;
  #pragma unroll
  for (int e = 0; e < 8; ++e) {
    float v = p[e];
    __bf16 h = (__bf16)v;
    o[e] = pl ? (__bf16)(v - (float)h) : h;
  }
  *(bf16x8*)dst = o;
}

// ---------------- depthwise conv1d -> t-major h0 (hi/lo bf16) ----------------
__global__ __launch_bounds__(256) void dwconv_t(
    const float* __restrict__ x, const float* __restrict__ w,
    const float* __restrict__ bias, __bf16* __restrict__ h0h,
    __bf16* __restrict__ h0l) {
  __shared__ float xs[64][76];
  const int tid = threadIdx.x;
  const int t0 = blockIdx.x * 64;
  const int n0 = blockIdx.y * 64;
  const int b = blockIdx.z;
  for (int i = tid; i < 64 * 72; i += 256) {
    int rr = i / 72, cc = i % 72;
    int tt = t0 - 4 + cc;
    xs[rr][cc] = (tt >= 0 && tt < T_) ? x[((size_t)(b * N_ + n0 + rr)) * T_ + tt] : 0.f;
  }
  const int nl = tid & 63;
  const int tg = tid >> 6;
  float wr[9];
  #pragma unroll
  for (int k = 0; k < 9; ++k) wr[k] = w[(n0 + nl) * 9 + k];
  const float bb = bias[n0 + nl];
  __syncthreads();
  float win[24];
  #pragma unroll
  for (int c = 0; c < 6; ++c)
    *(f32x4*)&win[c * 4] = *(const f32x4*)&xs[nl][tg * 16 + c * 4];
  const size_t obase = ((size_t)b * T_ + t0 + tg * 16) * N_ + n0 + nl;
  #pragma unroll
  for (int j = 0; j < 16; ++j) {
    float acc = bb;
    #pragma unroll
    for (int k = 0; k < 9; ++k) acc = fmaf(win[j + k], wr[k], acc);
    __bf16 h = (__bf16)acc;
    h0h[obase + (size_t)j * N_] = h;
    h0l[obase + (size_t)j * N_] = (__bf16)(acc - (float)h);
  }
}

// ---------------- fused encoder: gemm1 -> gemm2 -> heads ----------------
// 32 t-rows x full H=256 per block, 8 waves (2t x 4g), 3-pass split-bf16 MFMA,
// counted-vmcnt 2-deep pipeline (no vmcnt(0) drain in main loops).
__global__ __launch_bounds__(512) void encoder_fused(
    const __bf16* __restrict__ Ah, const __bf16* __restrict__ Al,
    const __bf16* __restrict__ W1P, const float* __restrict__ b1,
    const __bf16* __restrict__ W2P, const float* __restrict__ b2,
    const float* __restrict__ wm, const float* __restrict__ bm,
    const float* __restrict__ wv, const float* __restrict__ bv,
    float* __restrict__ out_mu, float* __restrict__ out_lv) {
  __shared__ __attribute__((aligned(16))) char smem[126976];
  char* const ASB = smem;                      // 2 buf x (2 pl x 2KB)
  char* const WSB = smem + 8192;               // 2 buf x 32KB
  char* const H1B = smem + 73728;              // 2 pl x 16KB, rows 512B
  float* const WMV = (float*)(smem + 106496);  // [256][20] f32
  float* const H2S = (float*)(smem + 8192);    // alias WSB: [32][264] f32

  const int tid = threadIdx.x;
  const int row0 = blockIdx.x * 32;
  const int lane = tid & 63;
  const int wid = tid >> 6;
  const int wt = (wid >> 2) * 16;  // wave t-offset (0/16)
  const int wg = (wid & 3) * 64;   // wave g-offset
  const int lr = lane & 15;
  const int ls = lane >> 4;

  // ---- init loads (MUST complete before pipeline: vmcnt bookkeeping) ----
  if (tid < 256) {
    #pragma unroll
    for (int i = 0; i < 8; ++i) WMV[tid * 20 + i] = wm[i * 256 + tid];
    #pragma unroll
    for (int i = 0; i < 4; ++i) WMV[tid * 20 + 8 + i] = wv[i * 256 + tid];
  }
  float b1g[4], b2g[4];
  #pragma unroll
  for (int ni = 0; ni < 4; ++ni) {
    b1g[ni] = b1[wg + ni * 16 + lr];
    b2g[ni] = b2[wg + ni * 16 + lr];
  }
  FENCE_ALL();

  // A staging map (tid<256): 1 gl16/thread/k-step, source-side XOR swizzle
  const int a_pl = tid >> 7;
  const int a_idx = tid & 127;
  const int a_r = a_idx >> 2;
  const int a_c = (a_idx & 3) ^ ((a_r >> 1) & 3);
  const __bf16* a_src = (a_pl ? Al : Ah) + (size_t)(row0 + a_r) * 1024 + a_c * 8;
  char* const a_dst = ASB + a_pl * 2048 + a_idx * 16;

  auto STAGE_A = [&](int buf, int kt) {
    if (tid < 256) gl16(a_src + kt * 32, a_dst + buf * 4096);
  };
  auto STAGE_W = [&](int buf, int kt, const __bf16* WP) {
    const char* src = (const char*)WP + (size_t)kt * 32768 + tid * 16;
    char* dst = WSB + buf * 32768 + tid * 16;
    #pragma unroll
    for (int j = 0; j < 4; ++j) gl16(src + j * 8192, dst + j * 8192);
  };
  auto FR_A = [&](int cur, int pl, int r) {
    return *(const bf16x8*)(ASB + cur * 4096 + pl * 2048 + r * 64 +
                            (ls ^ ((r >> 1) & 3)) * 16);
  };
  auto FR_W = [&](int cur, int pl, int g) {
    return *(const bf16x8*)(WSB + cur * 32768 + pl * 16384 + g * 64 +
                            (ls ^ ((g >> 1) & 3)) * 16);
  };

  f32x4 acc[4];
  #pragma unroll
  for (int i = 0; i < 4; ++i) acc[i] = (f32x4)0.f;

  // ---- gemm1: K=1024, 32 kt, 2-deep counted pipeline ----
  STAGE_A(0, 0); STAGE_W(0, 0, W1P);
  STAGE_A(1, 1); STAGE_W(1, 1, W1P);
  for (int kt = 0; kt < 32; ++kt) {
    const int cur = kt & 1;
    if (kt < 31) {
      if (tid < 256) WAITV(5); else WAITV(4);
    } else {
      WAITV(0);
    }
    __builtin_amdgcn_s_barrier();
    {
      const int ra = wt + lr;
      bf16x8 ah = FR_A(cur, 0, ra);
      bf16x8 al = FR_A(cur, 1, ra);
      __builtin_amdgcn_s_setprio(1);
      #pragma unroll
      for (int ni = 0; ni < 4; ++ni) {
        const int rw = wg + ni * 16 + lr;
        bf16x8 wh = FR_W(cur, 0, rw);
        bf16x8 wl = FR_W(cur, 1, rw);
        acc[ni] = __builtin_amdgcn_mfma_f32_16x16x32_bf16(ah, wh, acc[ni], 0, 0, 0);
        acc[ni] = __builtin_amdgcn_mfma_f32_16x16x32_bf16(ah, wl, acc[ni], 0, 0, 0);
        acc[ni] = __builtin_amdgcn_mfma_f32_16x16x32_bf16(al, wh, acc[ni], 0, 0, 0);
      }
      __builtin_amdgcn_s_setprio(0);
    }
    LGKM0();
    __builtin_amdgcn_s_barrier();
    if (kt < 30) { STAGE_A(cur, kt + 2); STAGE_W(cur, kt + 2, W1P); }
  }

  // ---- epilogue 1 -> h1 LDS (hi/lo, 512B rows, (t&7) chunk swizzle) ----
  #pragma unroll
  for (int ni = 0; ni < 4; ++ni) {
    const int g = wg + ni * 16 + lr;
    const int c = g >> 3;
    #pragma unroll
    for (int reg = 0; reg < 4; ++reg) {
      const int t = wt + ls * 4 + reg;
      float v = fmaxf(acc[ni][reg] + b1g[ni], 0.f);
      __bf16 h = (__bf16)v;
      const int off = t * 512 + ((c ^ (t & 7)) * 16) + (g & 7) * 2;
      *(__bf16*)(H1B + off) = h;
      *(__bf16*)(H1B + 16384 + off) = (__bf16)(v - (float)h);
    }
    acc[ni] = (f32x4)0.f;
  }

  // ---- gemm2: K=256, 8 kt, same pipeline (W only: 4 loads/thread) ----
  STAGE_W(0, 0, W2P);
  STAGE_W(1, 1, W2P);
  for (int kt = 0; kt < 8; ++kt) {
    const int cur = kt & 1;
    if (kt < 7) WAITV(4); else WAITV(0);
    LGKM0();  // h1 ds_writes (kt=0) drained before barrier
    __builtin_amdgcn_s_barrier();
    {
      const int t = wt + lr;
      const int ca = ((kt * 4 + ls) ^ (t & 7)) * 16;
      bf16x8 ah = *(const bf16x8*)(H1B + t * 512 + ca);
      bf16x8 al = *(const bf16x8*)(H1B + 16384 + t * 512 + ca);
      __builtin_amdgcn_s_setprio(1);
      #pragma unroll
      for (int ni = 0; ni < 4; ++ni) {
        const int rw = wg + ni * 16 + lr;
        bf16x8 wh = FR_W(cur, 0, rw);
        bf16x8 wl = FR_W(cur, 1, rw);
        acc[ni] = __builtin_amdgcn_mfma_f32_16x16x32_bf16(ah, wh, acc[ni], 0, 0, 0);
        acc[ni] = __builtin_amdgcn_mfma_f32_16x16x32_bf16(ah, wl, acc[ni], 0, 0, 0);
        acc[ni] = __builtin_amdgcn_mfma_f32_16x16x32_bf16(al, wh, acc[ni], 0, 0, 0);
      }
      __builtin_amdgcn_s_setprio(0);
    }
    LGKM0();
    __builtin_amdgcn_s_barrier();
    if (kt < 6) STAGE_W(cur, kt + 2, W2P);
  }

  // ---- epilogue 2 -> h2 f32 in LDS (aliases WSB; safe after final barrier) ----
  #pragma unroll
  for (int ni = 0; ni < 4; ++ni) {
    const int g = wg + ni * 16 + lr;
    #pragma unroll
    for (int reg = 0; reg < 4; ++reg) {
      const int t = wt + ls * 4 + reg;
      H2S[t * 264 + g] = fmaxf(acc[ni][reg] + b2g[ni], 0.f);
    }
  }
  LGKM0();
  __builtin_amdgcn_s_barrier();

  // ---- heads: 16 threads per t-row ----
  const int ht = tid >> 4;
  const int sub = tid & 15;
  float s[12];
  #pragma unroll
  for (int o = 0; o < 12; ++o) s[o] = 0.f;
  #pragma unroll
  for (int j = 0; j < 16; ++j) {
    const int k = sub + j * 16;
    const float hv = H2S[ht * 264 + k];
    const float* wp = &WMV[k * 20];
    #pragma unroll
    for (int o = 0; o < 12; ++o) s[o] = fmaf(wp[o], hv, s[o]);
  }
  #pragma unroll
  for (int o = 0; o < 12; ++o) {
    s[o] += __shfl_xor(s[o], 1);
    s[o] += __shfl_xor(s[o], 2);
    s[o] += __shfl_xor(s[o], 4);
    s[o] += __shfl_xor(s[o], 8);
  }
  const size_t row = row0 + ht;
  if (sub == 0) {
    float mm[8];
    #pragma unroll
    for (int ed = 0; ed < 4; ++ed) {
      float m0 = s[ed * 2] + bm[ed * 2];
      float m1 = s[ed * 2 + 1] + bm[ed * 2 + 1];
      float inv = 1.f / sqrtf(m0 * m0 + m1 * m1);
      mm[ed * 2] = m0 * inv;
      mm[ed * 2 + 1] = m1 * inv;
    }
    *(float4*)&out_mu[row * 8] = make_float4(mm[0], mm[1], mm[2], mm[3]);
    *(float4*)&out_mu[row * 8 + 4] = make_float4(mm[4], mm[5], mm[6], mm[7]);
  } else if (sub == 1) {
    *(float4*)&out_lv[row * 4] =
        make_float4(s[8] + bv[0], s[9] + bv[1], s[10] + bv[2], s[11] + bv[3]);
  }
}

// ---------------- responses + z copy ----------------
__global__ __launch_bounds__(256) void resp_kernel(
    const float* __restrict__ z, const float* __restrict__ rf,
    const float* __restrict__ ew, const float* __restrict__ fs,
    const float* __restrict__ ltw, float* __restrict__ out,
    float* __restrict__ out_z) {
  __shared__ float s_sin[32][4], s_cos[32][4], s_w[32][2];
  const int tid = threadIdx.x;
  const int tc = blockIdx.x;
  const int nc = blockIdx.y;
  const int b = blockIdx.z;
  if (tid < 128) {
    int nl = tid >> 2, ed = tid & 3;
    float a = rf[(nc * 32 + nl) * 4 + ed];
    s_sin[nl][ed] = sinf(a);
    s_cos[nl][ed] = cosf(a);
  }
  if (tid < 32) {
    int n = nc * 32 + tid;
    float e0 = ew[n * 2], e1 = ew[n * 2 + 1];
    float m = fmaxf(e0, e1);
    float x0 = expf(e0 - m), x1 = expf(e1 - m);
    float sc = expf(fs[n]) / (x0 + x1);
    s_w[tid][0] = x0 * sc;
    s_w[tid][1] = x1 * sc;
  }
  __syncthreads();
  const int t = tc * 1024 + (tid >> 6) * 256 + (tid & 63) * 4;
  const float inv_tw = expf(-ltw[0]);
  float sz[16], cz[16];
  #pragma unroll
  for (int j = 0; j < 4; ++j) {
    float4 zv = *(const float4*)&z[((size_t)b * T_ + t + j) * 4];
    if (nc == 0) *(float4*)&out_z[((size_t)b * T_ + t + j) * 4] = zv;
    sz[j * 4 + 0] = sinf(zv.x); cz[j * 4 + 0] = cosf(zv.x);
    sz[j * 4 + 1] = sinf(zv.y); cz[j * 4 + 1] = cosf(zv.y);
    sz[j * 4 + 2] = sinf(zv.z); cz[j * 4 + 2] = cosf(zv.z);
    sz[j * 4 + 3] = sinf(zv.w); cz[j * 4 + 3] = cosf(zv.w);
  }
  float* op = out + (size_t)b * N_ * T_ + (size_t)(nc * 32) * T_ + t;
  for (int nl = 0; nl < 32; ++nl) {
    const float ss0 = s_sin[nl][0], sc0 = s_cos[nl][0];
    const float ss1 = s_sin[nl][1], sc1 = s_cos[nl][1];
    const float ss2 = s_sin[nl][2], sc2 = s_cos[nl][2];
    const float ss3 = s_sin[nl][3], sc3 = s_cos[nl][3];
    const float w0 = s_w[nl][0], w1 = s_w[nl][1];
    float o[4];
    #pragma unroll
    for (int j = 0; j < 4; ++j) {
      float d0 = sz[j * 4] * ss0 + cz[j * 4] * sc0 + sz[j * 4 + 1] * ss1 + cz[j * 4 + 1] * sc1;
      float d1 = sz[j * 4 + 2] * ss2 + cz[j * 4 + 2] * sc2 + sz[j * 4 + 3] * ss3 + cz[j * 4 + 3] * sc3;
      float r0 = __expf((2.f * d0 - 4.f) * inv_tw);
      float r1 = __expf((2.f * d1 - 4.f) * inv_tw);
      o[j] = w0 * r0 + w1 * r1;
    }
    *(float4*)&op[(size_t)nl * T_] = make_float4(o[0], o[1], o[2], o[3]);
  }
}

extern "C" void kernel_launch(void* const* d_in, const int* in_sizes, int n_in,
                              void* d_out, int out_size, void* d_ws, size_t ws_size,
                              hipStream_t stream) {
  const float* x   = (const float*)d_in[0];
  const float* z   = (const float*)d_in[1];
  const float* dww = (const float*)d_in[2];
  const float* dwb = (const float*)d_in[3];
  const float* w1  = (const float*)d_in[4];
  const float* b1  = (const float*)d_in[5];
  const float* w2  = (const float*)d_in[6];
  const float* b2  = (const float*)d_in[7];
  const float* wm  = (const float*)d_in[8];
  const float* bm  = (const float*)d_in[9];
  const float* wv  = (const float*)d_in[10];
  const float* bv  = (const float*)d_in[11];
  const float* rf  = (const float*)d_in[12];
  const float* ew  = (const float*)d_in[13];
  const float* fs  = (const float*)d_in[14];
  const float* ltw = (const float*)d_in[15];

  float* out = (float*)d_out;
  float* out_resp = out;                          // [B,N,T]
  float* out_z    = out + (size_t)B_ * N_ * T_;   // [B,T,2,2]
  float* out_mu   = out_z + (size_t)B_ * T_ * 4;  // [B,T,2,2,2]
  float* out_lv   = out_mu + (size_t)B_ * T_ * 8; // [B,T,2,2]

  // h0 hi/lo planes live in the responses output region (same 33.55MB),
  // dead before resp_kernel runs (stream-ordered).
  __bf16* h0h = (__bf16*)out_resp;
  __bf16* h0l = h0h + (size_t)ROWS_ * N_;

  __bf16* p = (__bf16*)d_ws;
  __bf16* w1p = p; p += 524288;  // 32 kt x 2048 slots x 8 bf16
  __bf16* w2p = p; p += 131072;  // 8 kt x 2048 slots x 8 bf16

  cvt_pack<<<320, 256, 0, stream>>>(w1, w2, w1p, w2p);
  dwconv_t<<<dim3(T_ / 64, N_ / 64, B_), 256, 0, stream>>>(x, dww, dwb, h0h, h0l);
  encoder_fused<<<dim3(ROWS_ / 32), 512, 0, stream>>>(
      h0h, h0l, w1p, b1, w2p, b2, wm, bm, wv, bv, out_mu, out_lv);
  resp_kernel<<<dim3(4, 32, 2), 256, 0, stream>>>(
      z, rf, ew, fs, ltw, out_resp, out_z);
}

// Round 7
// 163.608 us; speedup vs baseline: 1.1396x; 1.0748x over previous
//
#include <hip/hip_runtime.h>
#include <hip/hip_bf16.h>

#define B_ 2
#define N_ 1024
#define T_ 4096
#define H_ 256
#define ROWS_ 8192     // B*T
#define ENC_BLOCKS 128 // encoder tiles of 64 rows

typedef float f32x4 __attribute__((ext_vector_type(4)));
typedef __bf16 bf16x8 __attribute__((ext_vector_type(8)));

__device__ __forceinline__ void gl16(const void* g, void* l) {
  __builtin_amdgcn_global_load_lds(
      (const __attribute__((address_space(1))) void*)g,
      (__attribute__((address_space(3))) void*)l, 16, 0, 0);
}

#define WAITV(N) asm volatile("s_waitcnt vmcnt(" #N ")" ::: "memory")
#define FENCE_ALL() asm volatile("s_waitcnt vmcnt(0) lgkmcnt(0)" ::: "memory")
#define LGKM0() asm volatile("s_waitcnt lgkmcnt(0)" ::: "memory")

// ---------------- pack W1/W2 into LDS-staging order (hi/lo bf16) ----------------
// slot s (0..2047) of k-tile kt: pl=s>>10, idx=s&1023, g=idx>>2,
// cc=(idx&3)^((g>>1)&3); content = plane_pl(W[g][kt*32+cc*8 .. +8))
__global__ __launch_bounds__(256) void cvt_pack(
    const float* __restrict__ w1, const float* __restrict__ w2,
    __bf16* __restrict__ w1p, __bf16* __restrict__ w2p) {
  const int i = blockIdx.x * 256 + threadIdx.x;
  const float* src;
  __bf16* dst;
  int K, kt, s;
  if (i < 65536) {
    kt = i >> 11; s = i & 2047; src = w1; K = 1024; dst = w1p + (size_t)i * 8;
  } else {
    int j = i - 65536;
    kt = j >> 11; s = j & 2047; src = w2; K = 256; dst = w2p + (size_t)j * 8;
  }
  const int pl = s >> 10;
  const int idx = s & 1023;
  const int g = idx >> 2;
  const int cc = (idx & 3) ^ ((g >> 1) & 3);
  const float* p = src + (size_t)g * K + kt * 32 + cc * 8;
  bf16x8 o;
  #pragma unroll
  for (int e = 0; e < 8; ++e) {
    float v = p[e];
    __bf16 h = (__bf16)v;
    o[e] = pl ? (__bf16)(v - (float)h) : h;
  }
  *(bf16x8*)dst = o;
}

// ---------------- depthwise conv1d -> t-major h0 (hi/lo bf16) ----------------
__global__ __launch_bounds__(256) void dwconv_t(
    const float* __restrict__ x, const float* __restrict__ w,
    const float* __restrict__ bias, __bf16* __restrict__ h0h,
    __bf16* __restrict__ h0l) {
  __shared__ float xs[64][76];
  const int tid = threadIdx.x;
  const int t0 = blockIdx.x * 64;
  const int n0 = blockIdx.y * 64;
  const int b = blockIdx.z;
  for (int i = tid; i < 64 * 72; i += 256) {
    int rr = i / 72, cc = i % 72;
    int tt = t0 - 4 + cc;
    xs[rr][cc] = (tt >= 0 && tt < T_) ? x[((size_t)(b * N_ + n0 + rr)) * T_ + tt] : 0.f;
  }
  const int nl = tid & 63;
  const int tg = tid >> 6;
  float wr[9];
  #pragma unroll
  for (int k = 0; k < 9; ++k) wr[k] = w[(n0 + nl) * 9 + k];
  const float bb = bias[n0 + nl];
  __syncthreads();
  float win[24];
  #pragma unroll
  for (int c = 0; c < 6; ++c)
    *(f32x4*)&win[c * 4] = *(const f32x4*)&xs[nl][tg * 16 + c * 4];
  const size_t obase = ((size_t)b * T_ + t0 + tg * 16) * N_ + n0 + nl;
  #pragma unroll
  for (int j = 0; j < 16; ++j) {
    float acc = bb;
    #pragma unroll
    for (int k = 0; k < 9; ++k) acc = fmaf(win[j + k], wr[k], acc);
    __bf16 h = (__bf16)acc;
    h0h[obase + (size_t)j * N_] = h;
    h0l[obase + (size_t)j * N_] = (__bf16)(acc - (float)h);
  }
}

// ---------------- mega: encoder (blocks 0..127) || responses (128..255) ----------------
// encoder: 64 t-rows x full H=256, 8 waves (2t x 4g), 3-pass split-bf16 MFMA,
// counted-vmcnt 2-deep pipeline. LDS 156KB.
__global__ __launch_bounds__(512) void mega_kernel(
    const __bf16* __restrict__ Ah, const __bf16* __restrict__ Al,
    const __bf16* __restrict__ W1P, const float* __restrict__ b1,
    const __bf16* __restrict__ W2P, const float* __restrict__ b2,
    const float* __restrict__ wm, const float* __restrict__ bm,
    const float* __restrict__ wv, const float* __restrict__ bv,
    float* __restrict__ out_mu, float* __restrict__ out_lv,
    const float* __restrict__ z, const float* __restrict__ rf,
    const float* __restrict__ ew, const float* __restrict__ fs,
    const float* __restrict__ ltw, float* __restrict__ out_resp,
    float* __restrict__ out_z) {
  __shared__ __attribute__((aligned(16))) char smem[159744];
  const int tid = threadIdx.x;

  if (blockIdx.x >= ENC_BLOCKS) {
    // ================= responses branch =================
    float* s_sin = (float*)smem;            // [32][4]
    float* s_cos = (float*)(smem + 512);    // [32][4]
    float* s_w   = (float*)(smem + 1024);   // [32][2]
    const int bid2 = blockIdx.x - ENC_BLOCKS;
    const int nc = bid2 & 31;         // n-chunk of 32
    const int tc = (bid2 >> 5) & 1;   // t-chunk of 2048
    const int b = bid2 >> 6;
    if (tid < 128) {
      int nl = tid >> 2, ed = tid & 3;
      float a = rf[(nc * 32 + nl) * 4 + ed];
      s_sin[nl * 4 + ed] = sinf(a);
      s_cos[nl * 4 + ed] = cosf(a);
    }
    if (tid < 32) {
      int n = nc * 32 + tid;
      float e0 = ew[n * 2], e1 = ew[n * 2 + 1];
      float m = fmaxf(e0, e1);
      float x0 = expf(e0 - m), x1 = expf(e1 - m);
      float sc = expf(fs[n]) / (x0 + x1);
      s_w[tid * 2 + 0] = x0 * sc;
      s_w[tid * 2 + 1] = x1 * sc;
    }
    __syncthreads();
    const int t = tc * 2048 + tid * 4;
    const float inv_tw = expf(-ltw[0]);
    float sz[16], cz[16];
    #pragma unroll
    for (int j = 0; j < 4; ++j) {
      float4 zv = *(const float4*)&z[((size_t)b * T_ + t + j) * 4];
      if (nc == 0) *(float4*)&out_z[((size_t)b * T_ + t + j) * 4] = zv;
      sz[j * 4 + 0] = sinf(zv.x); cz[j * 4 + 0] = cosf(zv.x);
      sz[j * 4 + 1] = sinf(zv.y); cz[j * 4 + 1] = cosf(zv.y);
      sz[j * 4 + 2] = sinf(zv.z); cz[j * 4 + 2] = cosf(zv.z);
      sz[j * 4 + 3] = sinf(zv.w); cz[j * 4 + 3] = cosf(zv.w);
    }
    float* op = out_resp + (size_t)b * N_ * T_ + (size_t)(nc * 32) * T_ + t;
    for (int nl = 0; nl < 32; ++nl) {
      const float ss0 = s_sin[nl * 4 + 0], sc0 = s_cos[nl * 4 + 0];
      const float ss1 = s_sin[nl * 4 + 1], sc1 = s_cos[nl * 4 + 1];
      const float ss2 = s_sin[nl * 4 + 2], sc2 = s_cos[nl * 4 + 2];
      const float ss3 = s_sin[nl * 4 + 3], sc3 = s_cos[nl * 4 + 3];
      const float w0 = s_w[nl * 2 + 0], w1 = s_w[nl * 2 + 1];
      float o[4];
      #pragma unroll
      for (int j = 0; j < 4; ++j) {
        float d0 = sz[j * 4] * ss0 + cz[j * 4] * sc0 + sz[j * 4 + 1] * ss1 + cz[j * 4 + 1] * sc1;
        float d1 = sz[j * 4 + 2] * ss2 + cz[j * 4 + 2] * sc2 + sz[j * 4 + 3] * ss3 + cz[j * 4 + 3] * sc3;
        float r0 = __expf((2.f * d0 - 4.f) * inv_tw);
        float r1 = __expf((2.f * d1 - 4.f) * inv_tw);
        o[j] = w0 * r0 + w1 * r1;
      }
      *(float4*)&op[(size_t)nl * T_] = make_float4(o[0], o[1], o[2], o[3]);
    }
    return;
  }

  // ================= encoder branch =================
  // layout: [0,16K) A dbuf | [16K,80K) W dbuf | [80K,144K) H1 | [144K,156K) WMV
  char* const ASB = smem;
  char* const WSB = smem + 16384;
  char* const H1B = smem + 81920;
  float* const WMV = (float*)(smem + 147456);  // [256][12]
  float* const H2S = (float*)smem;             // alias A+W: [64][257] f32 (65792B)

  const int row0 = blockIdx.x * 64;
  const int lane = tid & 63;
  const int wid = tid >> 6;
  const int wt = (wid >> 2) * 32;  // wave t-offset {0,32}
  const int wg = (wid & 3) * 64;   // wave g-offset {0,64,128,192}
  const int lr = lane & 15;
  const int ls = lane >> 4;

  // ---- init loads (drained before pipeline: vmcnt bookkeeping) ----
  if (tid < 256) {
    #pragma unroll
    for (int i = 0; i < 8; ++i) WMV[tid * 12 + i] = wm[i * 256 + tid];
    #pragma unroll
    for (int i = 0; i < 4; ++i) WMV[tid * 12 + 8 + i] = wv[i * 256 + tid];
  }
  float b1g[4], b2g[4];
  #pragma unroll
  for (int ni = 0; ni < 4; ++ni) {
    b1g[ni] = b1[wg + ni * 16 + lr];
    b2g[ni] = b2[wg + ni * 16 + lr];
  }
  FENCE_ALL();

  // A staging: 512 threads, 1 gl16 each: pl=tid>>8, idx=tid&255 ->
  // row=idx>>2 (0..63), chunk=(idx&3)^((row>>1)&3)  (source-side XOR swizzle)
  const int a_pl = tid >> 8;
  const int a_idx = tid & 255;
  const int a_r = a_idx >> 2;
  const int a_c = (a_idx & 3) ^ ((a_r >> 1) & 3);
  const __bf16* a_src = (a_pl ? Al : Ah) + (size_t)(row0 + a_r) * 1024 + a_c * 8;
  char* const a_dst = ASB + a_pl * 4096 + a_idx * 16;

  auto STAGE_A = [&](int buf, int kt) {
    gl16(a_src + kt * 32, a_dst + buf * 8192);
  };
  auto STAGE_W = [&](int buf, int kt, const __bf16* WP) {
    const char* src = (const char*)WP + (size_t)kt * 32768 + tid * 16;
    char* dst = WSB + buf * 32768 + tid * 16;
    #pragma unroll
    for (int j = 0; j < 4; ++j) gl16(src + j * 8192, dst + j * 8192);
  };
  auto FR_A = [&](int cur, int pl, int r) {
    return *(const bf16x8*)(ASB + cur * 8192 + pl * 4096 + r * 64 +
                            (ls ^ ((r >> 1) & 3)) * 16);
  };
  auto FR_W = [&](int cur, int pl, int g) {
    return *(const bf16x8*)(WSB + cur * 32768 + pl * 16384 + g * 64 +
                            (ls ^ ((g >> 1) & 3)) * 16);
  };

  f32x4 acc[2][4];
  #pragma unroll
  for (int i = 0; i < 2; ++i)
    #pragma unroll
    for (int j = 0; j < 4; ++j) acc[i][j] = (f32x4)0.f;

  // ---- gemm1: K=1024, 32 kt, 2-deep counted pipeline (5 loads/thread/step) ----
  STAGE_A(0, 0); STAGE_W(0, 0, W1P);
  STAGE_A(1, 1); STAGE_W(1, 1, W1P);
  for (int kt = 0; kt < 32; ++kt) {
    const int cur = kt & 1;
    if (kt < 31) WAITV(5); else WAITV(0);
    __builtin_amdgcn_s_barrier();
    {
      bf16x8 ah[2], al[2];
      #pragma unroll
      for (int mi = 0; mi < 2; ++mi) {
        ah[mi] = FR_A(cur, 0, wt + mi * 16 + lr);
        al[mi] = FR_A(cur, 1, wt + mi * 16 + lr);
      }
      __builtin_amdgcn_s_setprio(1);
      #pragma unroll
      for (int ni = 0; ni < 4; ++ni) {
        const int rw = wg + ni * 16 + lr;
        bf16x8 wh = FR_W(cur, 0, rw);
        bf16x8 wl = FR_W(cur, 1, rw);
        #pragma unroll
        for (int mi = 0; mi < 2; ++mi) {
          acc[mi][ni] = __builtin_amdgcn_mfma_f32_16x16x32_bf16(ah[mi], wh, acc[mi][ni], 0, 0, 0);
          acc[mi][ni] = __builtin_amdgcn_mfma_f32_16x16x32_bf16(ah[mi], wl, acc[mi][ni], 0, 0, 0);
          acc[mi][ni] = __builtin_amdgcn_mfma_f32_16x16x32_bf16(al[mi], wh, acc[mi][ni], 0, 0, 0);
        }
      }
      __builtin_amdgcn_s_setprio(0);
    }
    LGKM0();
    __builtin_amdgcn_s_barrier();
    if (kt < 30) { STAGE_A(cur, kt + 2); STAGE_W(cur, kt + 2, W1P); }
  }

  // ---- epilogue 1 -> h1 LDS (hi/lo, 512B rows, (t&7) chunk swizzle) ----
  #pragma unroll
  for (int mi = 0; mi < 2; ++mi)
    #pragma unroll
    for (int ni = 0; ni < 4; ++ni) {
      const int g = wg + ni * 16 + lr;
      const int c = g >> 3;
      #pragma unroll
      for (int reg = 0; reg < 4; ++reg) {
        const int t = wt + mi * 16 + ls * 4 + reg;
        float v = fmaxf(acc[mi][ni][reg] + b1g[ni], 0.f);
        __bf16 h = (__bf16)v;
        const int off = t * 512 + ((c ^ (t & 7)) * 16) + (g & 7) * 2;
        *(__bf16*)(H1B + off) = h;
        *(__bf16*)(H1B + 32768 + off) = (__bf16)(v - (float)h);
      }
      acc[mi][ni] = (f32x4)0.f;
    }

  // ---- gemm2: K=256, 8 kt, counted pipeline (4 loads/thread/step) ----
  STAGE_W(0, 0, W2P);
  STAGE_W(1, 1, W2P);
  for (int kt = 0; kt < 8; ++kt) {
    const int cur = kt & 1;
    if (kt < 7) WAITV(4); else WAITV(0);
    LGKM0();  // h1 ds_writes (kt=0) drained before barrier
    __builtin_amdgcn_s_barrier();
    {
      bf16x8 ah[2], al[2];
      #pragma unroll
      for (int mi = 0; mi < 2; ++mi) {
        const int t = wt + mi * 16 + lr;
        const int ca = ((kt * 4 + ls) ^ (t & 7)) * 16;
        ah[mi] = *(const bf16x8*)(H1B + t * 512 + ca);
        al[mi] = *(const bf16x8*)(H1B + 32768 + t * 512 + ca);
      }
      __builtin_amdgcn_s_setprio(1);
      #pragma unroll
      for (int ni = 0; ni < 4; ++ni) {
        const int rw = wg + ni * 16 + lr;
        bf16x8 wh = FR_W(cur, 0, rw);
        bf16x8 wl = FR_W(cur, 1, rw);
        #pragma unroll
        for (int mi = 0; mi < 2; ++mi) {
          acc[mi][ni] = __builtin_amdgcn_mfma_f32_16x16x32_bf16(ah[mi], wh, acc[mi][ni], 0, 0, 0);
          acc[mi][ni] = __builtin_amdgcn_mfma_f32_16x16x32_bf16(ah[mi], wl, acc[mi][ni], 0, 0, 0);
          acc[mi][ni] = __builtin_amdgcn_mfma_f32_16x16x32_bf16(al[mi], wh, acc[mi][ni], 0, 0, 0);
        }
      }
      __builtin_amdgcn_s_setprio(0);
    }
    LGKM0();
    __builtin_amdgcn_s_barrier();
    if (kt < 6) STAGE_W(cur, kt + 2, W2P);
  }

  // ---- epilogue 2 -> h2 f32 in LDS (aliases A+W bufs; safe after final barrier) ----
  #pragma unroll
  for (int mi = 0; mi < 2; ++mi)
    #pragma unroll
    for (int ni = 0; ni < 4; ++ni) {
      const int g = wg + ni * 16 + lr;
      #pragma unroll
      for (int reg = 0; reg < 4; ++reg) {
        const int t = wt + mi * 16 + ls * 4 + reg;
        H2S[t * 257 + g] = fmaxf(acc[mi][ni][reg] + b2g[ni], 0.f);
      }
    }
  LGKM0();
  __builtin_amdgcn_s_barrier();

  // ---- heads: 8 threads per t-row ----
  const int ht = tid >> 3;   // 0..63
  const int sub = tid & 7;
  float s[12];
  #pragma unroll
  for (int o = 0; o < 12; ++o) s[o] = 0.f;
  #pragma unroll
  for (int j = 0; j < 32; ++j) {
    const int k = sub + j * 8;
    const float hv = H2S[ht * 257 + k];
    const float* wp = &WMV[k * 12];
    #pragma unroll
    for (int o = 0; o < 12; ++o) s[o] = fmaf(wp[o], hv, s[o]);
  }
  #pragma unroll
  for (int o = 0; o < 12; ++o) {
    s[o] += __shfl_xor(s[o], 1);
    s[o] += __shfl_xor(s[o], 2);
    s[o] += __shfl_xor(s[o], 4);
  }
  const size_t row = row0 + ht;
  if (sub == 0) {
    float mm[8];
    #pragma unroll
    for (int ed = 0; ed < 4; ++ed) {
      float m0 = s[ed * 2] + bm[ed * 2];
      float m1 = s[ed * 2 + 1] + bm[ed * 2 + 1];
      float inv = 1.f / sqrtf(m0 * m0 + m1 * m1);
      mm[ed * 2] = m0 * inv;
      mm[ed * 2 + 1] = m1 * inv;
    }
    *(float4*)&out_mu[row * 8] = make_float4(mm[0], mm[1], mm[2], mm[3]);
    *(float4*)&out_mu[row * 8 + 4] = make_float4(mm[4], mm[5], mm[6], mm[7]);
  } else if (sub == 1) {
    *(float4*)&out_lv[row * 4] =
        make_float4(s[8] + bv[0], s[9] + bv[1], s[10] + bv[2], s[11] + bv[3]);
  }
}

extern "C" void kernel_launch(void* const* d_in, const int* in_sizes, int n_in,
                              void* d_out, int out_size, void* d_ws, size_t ws_size,
                              hipStream_t stream) {
  const float* x   = (const float*)d_in[0];
  const float* z   = (const float*)d_in[1];
  const float* dww = (const float*)d_in[2];
  const float* dwb = (const float*)d_in[3];
  const float* w1  = (const float*)d_in[4];
  const float* b1  = (const float*)d_in[5];
  const float* w2  = (const float*)d_in[6];
  const float* b2  = (const float*)d_in[7];
  const float* wm  = (const float*)d_in[8];
  const float* bm  = (const float*)d_in[9];
  const float* wv  = (const float*)d_in[10];
  const float* bv  = (const float*)d_in[11];
  const float* rf  = (const float*)d_in[12];
  const float* ew  = (const float*)d_in[13];
  const float* fs  = (const float*)d_in[14];
  const float* ltw = (const float*)d_in[15];

  float* out = (float*)d_out;
  float* out_resp = out;                          // [B,N,T]
  float* out_z    = out + (size_t)B_ * N_ * T_;   // [B,T,2,2]
  float* out_mu   = out_z + (size_t)B_ * T_ * 4;  // [B,T,2,2,2]
  float* out_lv   = out_mu + (size_t)B_ * T_ * 8; // [B,T,2,2]

  __bf16* p = (__bf16*)d_ws;
  __bf16* w1p = p; p += 524288;            // 32 kt x 2048 slots x 8 bf16
  __bf16* w2p = p; p += 131072;            // 8 kt x 2048 slots x 8 bf16
  __bf16* h0h = p; p += (size_t)ROWS_ * N_;
  __bf16* h0l = p; p += (size_t)ROWS_ * N_;

  cvt_pack<<<320, 256, 0, stream>>>(w1, w2, w1p, w2p);
  dwconv_t<<<dim3(T_ / 64, N_ / 64, B_), 256, 0, stream>>>(x, dww, dwb, h0h, h0l);
  mega_kernel<<<dim3(256), 512, 0, stream>>>(
      h0h, h0l, w1p, b1, w2p, b2, wm, bm, wv, bv, out_mu, out_lv,
      z, rf, ew, fs, ltw, out_resp, out_z);
}